// Round 6
// baseline (625.633 us; speedup 1.0000x reference)
//
#include <hip/hip_runtime.h>

#define EPS 1e-5f

typedef __attribute__((ext_vector_type(8))) short short8v;
typedef __attribute__((ext_vector_type(4))) float f32x4;

__device__ __forceinline__ unsigned short f2bf(float f) {
    union { float f; unsigned int u; } v; v.f = f;
    unsigned int r = v.u + 0x7fffu + ((v.u >> 16) & 1u);
    return (unsigned short)(r >> 16);
}
__device__ __forceinline__ float bf2f(unsigned short h) {
    union { unsigned int u; float f; } v; v.u = ((unsigned int)h) << 16;
    return v.f;
}

// ---------------- degree count ----------------

__global__ __launch_bounds__(256) void count_deg(const int* __restrict__ dst, int* __restrict__ cnt, int E) {
    int i = blockIdx.x * 256 + threadIdx.x;
    if (i < E) atomicAdd(&cnt[dst[i]], 1);
}

__global__ __launch_bounds__(256) void calc_dis(const int* __restrict__ cnt, float* __restrict__ dis, int n) {
    int i = blockIdx.x * 256 + threadIdx.x;
    if (i < n) dis[i] = rsqrtf((float)cnt[i] + 1.0f);
}

// ---------------- exclusive scan (3-kernel) ----------------
__global__ __launch_bounds__(256) void scan1(const int* __restrict__ cnt, int* __restrict__ excl,
                                             int* __restrict__ bsum, int n) {
    __shared__ int sdata[256];
    const int tid = threadIdx.x;
    const int base = blockIdx.x * 1024 + tid * 4;
    int v0 = (base + 0 < n) ? cnt[base + 0] : 0;
    int v1 = (base + 1 < n) ? cnt[base + 1] : 0;
    int v2 = (base + 2 < n) ? cnt[base + 2] : 0;
    int v3 = (base + 3 < n) ? cnt[base + 3] : 0;
    int s = v0 + v1 + v2 + v3;
    sdata[tid] = s;
    __syncthreads();
    for (int off = 1; off < 256; off <<= 1) {
        int t = (tid >= off) ? sdata[tid - off] : 0;
        __syncthreads();
        sdata[tid] += t;
        __syncthreads();
    }
    if (tid == 255) bsum[blockIdx.x] = sdata[255];
    int run = sdata[tid] - s;
    if (base + 0 < n) excl[base + 0] = run; run += v0;
    if (base + 1 < n) excl[base + 1] = run; run += v1;
    if (base + 2 < n) excl[base + 2] = run; run += v2;
    if (base + 3 < n) excl[base + 3] = run;
}

__global__ __launch_bounds__(256) void scan2(int* __restrict__ bsum, int nb) {
    __shared__ int sdata[256];
    const int tid = threadIdx.x;
    int v = (tid < nb) ? bsum[tid] : 0;
    sdata[tid] = v;
    __syncthreads();
    for (int off = 1; off < 256; off <<= 1) {
        int t = (tid >= off) ? sdata[tid - off] : 0;
        __syncthreads();
        sdata[tid] += t;
        __syncthreads();
    }
    if (tid < nb) bsum[tid] = sdata[tid] - v;
}

// writes both rowptr and fill (= working copy for csr_fill's atomic cursor)
__global__ __launch_bounds__(256) void scan3(int* __restrict__ rowptr, int* __restrict__ fill,
                                             const int* __restrict__ bsum, int n, int E) {
    int i = blockIdx.x * 256 + threadIdx.x;
    if (i < n) {
        int v = rowptr[i] + bsum[i >> 10];
        rowptr[i] = v;
        fill[i] = v;
    }
    if (i == 0) rowptr[n] = E;
}

// ---------------- CSR fill: src-only entries, fill[] holds the running cursor ----------------
__global__ __launch_bounds__(256) void csr_fill(const int* __restrict__ src, const int* __restrict__ dst,
                                                int* __restrict__ fill, int* __restrict__ csr, int E) {
    int e = blockIdx.x * 256 + threadIdx.x;
    if (e >= E) return;
    int s = src[e], d = dst[e];
    int pos = atomicAdd(&fill[d], 1);
    csr[pos] = s;
}

// ---------------- x cast: xs = bf16(dis[node] * x[node][c]), padded 42 -> 48 ----------------
__global__ __launch_bounds__(256) void cast_x(const float* __restrict__ x, const float* __restrict__ dis,
                                              unsigned short* __restrict__ xs, int n) {
    int gid = blockIdx.x * 256 + threadIdx.x;
    int nd = gid / 48, c = gid - nd * 48;
    if (nd >= n) return;
    float v = (c < 42) ? x[(size_t)nd * 42 + c] * dis[nd] : 0.0f;
    xs[(size_t)nd * 48 + c] = f2bf(v);
}

// ---------------- W1 pad: [42][128] -> [48][128] (zero pad rows) ----------------
__global__ __launch_bounds__(256) void pad_w1(const float* __restrict__ W, float* __restrict__ Wp) {
    int i = blockIdx.x * 256 + threadIdx.x;
    if (i >= 48 * 128) return;
    int k = i >> 7;
    Wp[i] = (k < 42) ? W[i] : 0.0f;
}

// ---------------- W split: [K][DOUT] f32 -> transposed bf16 hi/lo [DOUT][K] ----------------
__global__ __launch_bounds__(256) void split_w(const float* __restrict__ W, unsigned short* __restrict__ hi,
                                               unsigned short* __restrict__ lo, int K, int DOUT, int Kpad) {
    int i = blockIdx.x * 256 + threadIdx.x;
    if (i >= DOUT * Kpad) return;
    int c = i / Kpad, k = i - c * Kpad;
    float w = (k < K) ? W[(size_t)k * DOUT + c] : 0.0f;
    unsigned short h = f2bf(w);
    hi[i] = h;
    lo[i] = f2bf(w - bf2f(h));
}

// ---------------- bf16 prescaled aggregation: out[nd] = dis[nd] * (xs[nd] + sum xs[src]) ----------------
// FUSE 0: plain ; FUSE 1: relu(agg + (b*s+t))
template<int D, int FUSE>
__global__ __launch_bounds__(256) void agg_bf(const unsigned short* __restrict__ x, const float* __restrict__ dis,
                                              const int* __restrict__ rowptr, const int* __restrict__ csr,
                                              const float* __restrict__ b, const float* __restrict__ g,
                                              const float* __restrict__ be, const float* __restrict__ rm,
                                              const float* __restrict__ rv,
                                              float* __restrict__ out, int n) {
    constexpr int CPE = D / 8;
    int gid = blockIdx.x * 256 + threadIdx.x;
    int nd = gid / CPE, c = gid - nd * CPE;
    if (nd >= n) return;

    float acc[8];
    {
        short8v v = *reinterpret_cast<const short8v*>(x + (size_t)nd * D + c * 8);
#pragma unroll
        for (int j = 0; j < 8; ++j) acc[j] = bf2f((unsigned short)v[j]);
    }
    const int r0 = rowptr[nd], r1 = rowptr[nd + 1];
    int i = r0;
    for (; i + 2 <= r1; i += 2) {
        int s0 = csr[i], s1 = csr[i + 1];
        short8v v0 = *reinterpret_cast<const short8v*>(x + (size_t)s0 * D + c * 8);
        short8v v1 = *reinterpret_cast<const short8v*>(x + (size_t)s1 * D + c * 8);
#pragma unroll
        for (int j = 0; j < 8; ++j) acc[j] += bf2f((unsigned short)v0[j]);
#pragma unroll
        for (int j = 0; j < 8; ++j) acc[j] += bf2f((unsigned short)v1[j]);
    }
    for (; i < r1; ++i) {
        int s0 = csr[i];
        short8v v = *reinterpret_cast<const short8v*>(x + (size_t)s0 * D + c * 8);
#pragma unroll
        for (int j = 0; j < 8; ++j) acc[j] += bf2f((unsigned short)v[j]);
    }

    float dn = dis[nd];
#pragma unroll
    for (int j = 0; j < 8; ++j) acc[j] *= dn;

    if (FUSE == 1) {
#pragma unroll
        for (int j = 0; j < 8; ++j) {
            int col = c * 8 + j;
            float sv = g[col] * rsqrtf(rv[col] + EPS);
            float bb = b[col] * sv + (be[col] - rm[col] * sv);
            acc[j] = fmaxf(acc[j] + bb, 0.0f);
        }
    }

    float4 o0, o1;
    o0.x = acc[0]; o0.y = acc[1]; o0.z = acc[2]; o0.w = acc[3];
    o1.x = acc[4]; o1.y = acc[5]; o1.z = acc[6]; o1.w = acc[7];
    float* op = out + (size_t)nd * D + c * 8;
    *reinterpret_cast<float4*>(op) = o0;
    *reinterpret_cast<float4*>(op + 4) = o1;
}

// ---------------- split-bf16 MFMA GEMM ----------------
// MODE 0: z=(acc+b)*s+t, relu ; MODE 1: z=acc*s ; MODE 2: z=relu(acc+b)*s+t
// OUTBF: write bf16 ; RS: multiply by dis[row] (prescale for next aggregation)
template<int K, int DOUT, int MODE, int OUTBF, int RS>
__global__ __launch_bounds__(256) void gemm_mfma(const float* __restrict__ X,
                                                 const unsigned short* __restrict__ Wh,
                                                 const unsigned short* __restrict__ Wl,
                                                 const float* __restrict__ b, const float* __restrict__ g,
                                                 const float* __restrict__ be, const float* __restrict__ rm,
                                                 const float* __restrict__ rv, const float* __restrict__ dis,
                                                 void* __restrict__ outv, int n) {
    constexpr int BN = (DOUT < 128) ? DOUT : 128;
    constexpr int NT = BN / 16;
    constexpr int KSTEPS = K / 32;
    constexpr int LDA = 40;
    __shared__ unsigned short xh[64][LDA], xl[64][LDA];
    __shared__ unsigned short wh[BN][LDA], wl[BN][LDA];

    const int tid = threadIdx.x;
    const int wave = tid >> 6, lane = tid & 63;
    const int row0 = blockIdx.x * 64;
    const int col0 = blockIdx.y * BN;
    const int r_l = lane & 15;
    const int k_l = (lane >> 4) * 8;

    f32x4 acc[NT];
#pragma unroll
    for (int t = 0; t < NT; ++t) acc[t] = (f32x4){0.f, 0.f, 0.f, 0.f};

    for (int ks = 0; ks < KSTEPS; ++ks) {
        const int k0 = ks * 32;
        for (int i = tid; i < 64 * 8; i += 256) {
            int m = i >> 3, q = i & 7;
            int rr = row0 + m;
            float4 v = (rr < n) ? *reinterpret_cast<const float4*>(X + (size_t)rr * K + k0 + q * 4)
                                : make_float4(0.f, 0.f, 0.f, 0.f);
            unsigned short h0 = f2bf(v.x), h1 = f2bf(v.y), h2 = f2bf(v.z), h3 = f2bf(v.w);
            unsigned short l0 = f2bf(v.x - bf2f(h0)), l1 = f2bf(v.y - bf2f(h1));
            unsigned short l2 = f2bf(v.z - bf2f(h2)), l3 = f2bf(v.w - bf2f(h3));
            uint2 ph = make_uint2((unsigned)h0 | ((unsigned)h1 << 16), (unsigned)h2 | ((unsigned)h3 << 16));
            uint2 pl = make_uint2((unsigned)l0 | ((unsigned)l1 << 16), (unsigned)l2 | ((unsigned)l3 << 16));
            *reinterpret_cast<uint2*>(&xh[m][q * 4]) = ph;
            *reinterpret_cast<uint2*>(&xl[m][q * 4]) = pl;
        }
        for (int i = tid; i < BN * 4; i += 256) {
            int cc = i >> 2, q = i & 3;
            size_t goff = (size_t)(col0 + cc) * K + k0 + q * 8;
            *reinterpret_cast<uint4*>(&wh[cc][q * 8]) = *reinterpret_cast<const uint4*>(Wh + goff);
            *reinterpret_cast<uint4*>(&wl[cc][q * 8]) = *reinterpret_cast<const uint4*>(Wl + goff);
        }
        __syncthreads();

        short8v ah = *reinterpret_cast<const short8v*>(&xh[wave * 16 + r_l][k_l]);
        short8v al = *reinterpret_cast<const short8v*>(&xl[wave * 16 + r_l][k_l]);
#pragma unroll
        for (int t = 0; t < NT; ++t) {
            short8v bh = *reinterpret_cast<const short8v*>(&wh[t * 16 + r_l][k_l]);
            short8v bl = *reinterpret_cast<const short8v*>(&wl[t * 16 + r_l][k_l]);
            acc[t] = __builtin_amdgcn_mfma_f32_16x16x32_bf16(ah, bh, acc[t], 0, 0, 0);
            acc[t] = __builtin_amdgcn_mfma_f32_16x16x32_bf16(al, bh, acc[t], 0, 0, 0);
            acc[t] = __builtin_amdgcn_mfma_f32_16x16x32_bf16(ah, bl, acc[t], 0, 0, 0);
        }
        __syncthreads();
    }

    const int orow = row0 + wave * 16 + (lane >> 4) * 4;
    float dsc[4];
#pragma unroll
    for (int r = 0; r < 4; ++r)
        dsc[r] = (RS && orow + r < n) ? dis[orow + r] : 1.0f;

#pragma unroll
    for (int t = 0; t < NT; ++t) {
        int col = col0 + t * 16 + r_l;
        float s, tt, bias;
        if (MODE == 0 || MODE == 2) {
            float sv = g[col] * rsqrtf(rv[col] + EPS);
            s = sv; tt = be[col] - rm[col] * sv; bias = b[col];
        } else {
            s = g[col] * rsqrtf(rv[col] + EPS); tt = 0.f; bias = 0.f;
        }
#pragma unroll
        for (int r = 0; r < 4; ++r) {
            int rr = orow + r;
            if (rr < n) {
                float z = acc[t][r];
                if (MODE == 0)      { z = (z + bias) * s + tt; z = fmaxf(z, 0.0f); }
                else if (MODE == 1) { z = z * s; }
                else                { z = fmaxf(z + bias, 0.0f) * s + tt; }
                if (RS) z *= dsc[r];
                if (OUTBF) ((unsigned short*)outv)[(size_t)rr * DOUT + col] = f2bf(z);
                else       ((float*)outv)[(size_t)rr * DOUT + col] = z;
            }
        }
    }
}

// ---------------- f32 register-tiled GEMM ----------------
template<int K, int DOUT, int MODE, int OUTBF, int RS>
__global__ __launch_bounds__(256) void gemm_tile(const float* __restrict__ X, const float* __restrict__ W,
                                                 const float* __restrict__ b, const float* __restrict__ g,
                                                 const float* __restrict__ be, const float* __restrict__ rm,
                                                 const float* __restrict__ rv, const float* __restrict__ dis,
                                                 void* __restrict__ outv, int n) {
    constexpr int TM = 8;
    constexpr int TN = (DOUT >= 64) ? 8 : 4;
    constexpr int BN = (DOUT < 128) ? DOUT : 128;
    constexpr int BM = 256 * TM * TN / BN;
    constexpr int KT = (K % 32 == 0) ? 32 : K;
    constexpr int NTN = BN / TN;
    static_assert((BM / TM) * NTN == 256, "thread mapping");

    __shared__ float xs[BM][KT + 1];
    __shared__ float ws[KT][BN];

    const int tid = threadIdx.x;
    const int tn_idx = tid % NTN;
    const int tm_idx = tid / NTN;
    const int row0 = blockIdx.x * BM;
    const int col0 = blockIdx.y * BN;

    float acc[TM][TN];
#pragma unroll
    for (int i = 0; i < TM; ++i)
#pragma unroll
        for (int j = 0; j < TN; ++j) acc[i][j] = 0.0f;

    for (int k0 = 0; k0 < K; k0 += KT) {
        for (int i = tid; i < BM * KT / 4; i += 256) {
            int m = i / (KT / 4), kq = i - m * (KT / 4);
            int k = kq * 4;
            int rr = row0 + m;
            float4 v = (rr < n) ? *reinterpret_cast<const float4*>(X + (size_t)rr * K + k0 + k)
                                : make_float4(0.f, 0.f, 0.f, 0.f);
            xs[m][k + 0] = v.x; xs[m][k + 1] = v.y; xs[m][k + 2] = v.z; xs[m][k + 3] = v.w;
        }
        for (int i = tid; i < KT * BN / 4; i += 256) {
            int k = i / (BN / 4), cq = i - k * (BN / 4);
            float4 wv = *reinterpret_cast<const float4*>(W + (size_t)(k0 + k) * DOUT + col0 + cq * 4);
            *reinterpret_cast<float4*>(&ws[k][cq * 4]) = wv;
        }
        __syncthreads();

#pragma unroll 2
        for (int k = 0; k < KT; ++k) {
            float av[TM], bv[TN];
#pragma unroll
            for (int i = 0; i < TM; ++i) av[i] = xs[tm_idx * TM + i][k];
#pragma unroll
            for (int j = 0; j < TN; j += 4)
                *reinterpret_cast<float4*>(&bv[j]) = *reinterpret_cast<const float4*>(&ws[k][tn_idx * TN + j]);
#pragma unroll
            for (int i = 0; i < TM; ++i)
#pragma unroll
                for (int j = 0; j < TN; ++j)
                    acc[i][j] = fmaf(av[i], bv[j], acc[i][j]);
        }
        __syncthreads();
    }

    float s[TN], t[TN], bias[TN];
#pragma unroll
    for (int j = 0; j < TN; ++j) {
        int col = col0 + tn_idx * TN + j;
        if (MODE == 0 || MODE == 2) {
            float sv = g[col] * rsqrtf(rv[col] + EPS);
            s[j] = sv; t[j] = be[col] - rm[col] * sv; bias[j] = b[col];
        } else {
            s[j] = g[col] * rsqrtf(rv[col] + EPS); t[j] = 0.f; bias[j] = 0.f;
        }
    }

#pragma unroll
    for (int i = 0; i < TM; ++i) {
        int rr = row0 + tm_idx * TM + i;
        if (rr < n) {
            float dsc = RS ? dis[rr] : 1.0f;
            float o[TN];
#pragma unroll
            for (int j = 0; j < TN; ++j) {
                float z = acc[i][j];
                if (MODE == 0)      { z = (z + bias[j]) * s[j] + t[j]; z = fmaxf(z, 0.0f); }
                else if (MODE == 1) { z = z * s[j]; }
                else                { z = fmaxf(z + bias[j], 0.0f) * s[j] + t[j]; }
                if (RS) z *= dsc;
                o[j] = z;
            }
            if (OUTBF) {
                unsigned short* op = (unsigned short*)outv + (size_t)rr * DOUT + col0 + tn_idx * TN;
                unsigned int pk[TN / 2];
#pragma unroll
                for (int j2 = 0; j2 < TN / 2; ++j2)
                    pk[j2] = (unsigned)f2bf(o[2 * j2]) | ((unsigned)f2bf(o[2 * j2 + 1]) << 16);
#pragma unroll
                for (int j2 = 0; j2 < TN / 2; ++j2)
                    *reinterpret_cast<unsigned int*>(op + 2 * j2) = pk[j2];
            } else {
                float* op = (float*)outv + (size_t)rr * DOUT + col0 + tn_idx * TN;
#pragma unroll
                for (int j = 0; j < TN; j += 4)
                    *reinterpret_cast<float4*>(op + j) = *reinterpret_cast<const float4*>(&o[j]);
            }
        }
    }
}

// final Linear 32 -> 2
__global__ __launch_bounds__(256) void final_linear(const float* __restrict__ X, const float* __restrict__ W,
                                                    const float* __restrict__ b, float* __restrict__ out, int n) {
    int row = blockIdx.x * 256 + threadIdx.x;
    if (row >= n) return;
    float a0 = 0.0f, a1 = 0.0f;
#pragma unroll
    for (int k = 0; k < 32; ++k) {
        float xv = X[(size_t)row * 32 + k];
        a0 = fmaf(xv, W[k * 2 + 0], a0);
        a1 = fmaf(xv, W[k * 2 + 1], a1);
    }
    out[(size_t)row * 2 + 0] = a0 + b[0];
    out[(size_t)row * 2 + 1] = a1 + b[1];
}

// ---------------- launch ----------------

extern "C" void kernel_launch(void* const* d_in, const int* in_sizes, int n_in,
                              void* d_out, int out_size, void* d_ws, size_t ws_size,
                              hipStream_t stream) {
    const float* x  = (const float*)d_in[0];
    const int*   ei = (const int*)d_in[1];
    const int E = in_sizes[1] / 2;
    const int n = in_sizes[0] / 42;
    const int* src = ei;
    const int* dst = ei + E;

    const float *W1 = (const float*)d_in[2],  *b1 = (const float*)d_in[3],  *g1 = (const float*)d_in[4],
                *be1 = (const float*)d_in[5], *rm1 = (const float*)d_in[6], *rv1 = (const float*)d_in[7];
    const float *W2 = (const float*)d_in[8],  *b2 = (const float*)d_in[9],  *g2 = (const float*)d_in[10],
                *be2 = (const float*)d_in[11], *rm2 = (const float*)d_in[12], *rv2 = (const float*)d_in[13];
    const float *W3 = (const float*)d_in[14], *b3 = (const float*)d_in[15], *g3 = (const float*)d_in[16],
                *be3 = (const float*)d_in[17], *rm3 = (const float*)d_in[18], *rv3 = (const float*)d_in[19];
    const float *W4 = (const float*)d_in[20], *b4 = (const float*)d_in[21], *g4 = (const float*)d_in[22],
                *be4 = (const float*)d_in[23], *rm4 = (const float*)d_in[24], *rv4 = (const float*)d_in[25];
    const float *cW1 = (const float*)d_in[26], *cb1 = (const float*)d_in[27], *cg1 = (const float*)d_in[28],
                *cbe1 = (const float*)d_in[29], *crm1 = (const float*)d_in[30], *crv1 = (const float*)d_in[31];
    const float *cW2 = (const float*)d_in[32], *cb2 = (const float*)d_in[33], *cg2 = (const float*)d_in[34],
                *cbe2 = (const float*)d_in[35], *crm2 = (const float*)d_in[36], *crv2 = (const float*)d_in[37];
    const float *cW3 = (const float*)d_in[38], *cb3 = (const float*)d_in[39];

    // ---- workspace layout (16B-aligned blocks) ----
    int*   csr    = (int*)d_ws;                          // E (src-only)
    float* bufA   = (float*)(csr + ((E + 3) & ~3));      // n*128
    float* bufB   = bufA + (size_t)n * 128;              // n*256
    unsigned short* hbf = (unsigned short*)(bufB + (size_t)n * 256);  // n*128 bf16
    unsigned short* xs1 = hbf + (size_t)n * 128;         // n*48 bf16 (prescaled padded x)
    float* dis    = (float*)(xs1 + (size_t)n * 48);      // n
    int*   cnt    = (int*)(dis + n);                     // n
    int*   fill   = cnt + n;                             // n
    int*   rowptr = fill + n;                            // n+1
    int*   bsum   = rowptr + n + 1;                      // 256
    float* W1p    = (float*)(bsum + 256);                // 48*128
    unsigned short* w2h = (unsigned short*)(W1p + 48 * 128);  // 256*128
    unsigned short* w2l = w2h + 256 * 128;
    unsigned short* w3h = w2l + 256 * 128;               // 128*256
    unsigned short* w3l = w3h + 128 * 256;
    unsigned short* w4h = w3l + 128 * 256;               // 64*128
    unsigned short* w4l = w4h + 64 * 128;

    dim3 blk(256);
    auto nb = [](long total) { return dim3((unsigned)((total + 255) / 256)); };
    const int nscan = (n + 1023) / 1024;
    const float* nul = nullptr;

    // ---- CSR build + weight prep ----
    hipMemsetAsync(cnt, 0, (size_t)n * sizeof(int), stream);
    count_deg<<<nb(E), blk, 0, stream>>>(dst, cnt, E);
    calc_dis<<<nb(n), blk, 0, stream>>>(cnt, dis, n);
    scan1<<<dim3(nscan), blk, 0, stream>>>(cnt, rowptr, bsum, n);
    scan2<<<dim3(1), blk, 0, stream>>>(bsum, nscan);
    scan3<<<nb(n), blk, 0, stream>>>(rowptr, fill, bsum, n, E);
    csr_fill<<<nb(E), blk, 0, stream>>>(src, dst, fill, csr, E);
    cast_x<<<nb((long)n * 48), blk, 0, stream>>>(x, dis, xs1, n);
    pad_w1<<<nb(48 * 128), blk, 0, stream>>>(W1, W1p);
    split_w<<<nb(256 * 128), blk, 0, stream>>>(W2, w2h, w2l, 128, 256, 128);
    split_w<<<nb(128 * 256), blk, 0, stream>>>(W3, w3h, w3l, 256, 128, 256);
    split_w<<<nb(64 * 128),  blk, 0, stream>>>(W4, w4h, w4l, 128, 64, 128);

    // ---- Layer 1: agg_bf<48>(xs1)->bufA ; gemm 48->128 BN+ReLU, row-scale, bf16 -> hbf
    agg_bf<48, 0><<<nb((long)n * 6), blk, 0, stream>>>(xs1, dis, rowptr, csr, nul, nul, nul, nul, nul, bufA, n);
    gemm_tile<48, 128, 0, 1, 1><<<dim3((n + 127) / 128, 1), blk, 0, stream>>>(bufA, W1p, b1, g1, be1, rm1, rv1, dis, (void*)hbf, n);

    // ---- Layer 2: agg_bf<128>(hbf)->bufA ; gemm 128->256 BN+ReLU -> bufB (f32, no scale)
    agg_bf<128, 0><<<nb((long)n * 16), blk, 0, stream>>>(hbf, dis, rowptr, csr, nul, nul, nul, nul, nul, bufA, n);
    gemm_mfma<128, 256, 0, 0, 0><<<dim3((n + 63) / 64, 2), blk, 0, stream>>>(bufA, w2h, w2l, b2, g2, be2, rm2, rv2, nul, (void*)bufB, n);

    // ---- Layer 3: gemm 256->128 (col-scale s3, row-scale dis) -> hbf ; agg + fused bias/bn/relu -> bufA
    gemm_mfma<256, 128, 1, 1, 1><<<dim3((n + 63) / 64, 1), blk, 0, stream>>>(bufB, w3h, w3l, b3, g3, be3, rm3, rv3, dis, (void*)hbf, n);
    agg_bf<128, 1><<<nb((long)n * 16), blk, 0, stream>>>(hbf, dis, rowptr, csr, b3, g3, be3, rm3, rv3, bufA, n);

    // ---- Layer 4: gemm 128->64 (col-scale s4, row-scale dis) -> hbf ; agg + fused bias/bn/relu -> bufB
    gemm_mfma<128, 64, 1, 1, 1><<<dim3((n + 63) / 64, 1), blk, 0, stream>>>(bufA, w4h, w4l, b4, g4, be4, rm4, rv4, dis, (void*)hbf, n);
    agg_bf<64, 1><<<nb((long)n * 8), blk, 0, stream>>>(hbf, dis, rowptr, csr, b4, g4, be4, rm4, rv4, bufB, n);

    // ---- Classifier
    gemm_tile<64, 64, 2, 0, 0><<<dim3((n + 255) / 256, 1), blk, 0, stream>>>(bufB, cW1, cb1, cg1, cbe1, crm1, crv1, nul, (void*)bufA, n);
    gemm_tile<64, 32, 2, 0, 0><<<dim3((n + 255) / 256, 1), blk, 0, stream>>>(bufA, cW2, cb2, cg2, cbe2, crm2, crv2, nul, (void*)bufB, n);
    final_linear<<<nb(n), blk, 0, stream>>>(bufB, cW3, cb3, (float*)d_out, n);
}

// Round 7
// 616.962 us; speedup vs baseline: 1.0141x; 1.0141x over previous
//
#include <hip/hip_runtime.h>

#define EPS 1e-5f

typedef __attribute__((ext_vector_type(8))) short short8v;
typedef __attribute__((ext_vector_type(4))) float f32x4;

__device__ __forceinline__ unsigned short f2bf(float f) {
    union { float f; unsigned int u; } v; v.f = f;
    unsigned int r = v.u + 0x7fffu + ((v.u >> 16) & 1u);
    return (unsigned short)(r >> 16);
}
__device__ __forceinline__ float bf2f(unsigned short h) {
    union { unsigned int u; float f; } v; v.u = ((unsigned int)h) << 16;
    return v.f;
}

// ---------------- degree count ----------------

__global__ __launch_bounds__(256) void count_deg(const int* __restrict__ dst, int* __restrict__ cnt, int E) {
    int i = blockIdx.x * 256 + threadIdx.x;
    if (i < E) atomicAdd(&cnt[dst[i]], 1);
}

// ---------------- exclusive scan (3-kernel), scan1 also emits dis ----------------
__global__ __launch_bounds__(256) void scan1(const int* __restrict__ cnt, int* __restrict__ excl,
                                             int* __restrict__ bsum, float* __restrict__ dis, int n) {
    __shared__ int sdata[256];
    const int tid = threadIdx.x;
    const int base = blockIdx.x * 1024 + tid * 4;
    int v0 = (base + 0 < n) ? cnt[base + 0] : 0;
    int v1 = (base + 1 < n) ? cnt[base + 1] : 0;
    int v2 = (base + 2 < n) ? cnt[base + 2] : 0;
    int v3 = (base + 3 < n) ? cnt[base + 3] : 0;
    if (base + 0 < n) dis[base + 0] = rsqrtf((float)v0 + 1.0f);
    if (base + 1 < n) dis[base + 1] = rsqrtf((float)v1 + 1.0f);
    if (base + 2 < n) dis[base + 2] = rsqrtf((float)v2 + 1.0f);
    if (base + 3 < n) dis[base + 3] = rsqrtf((float)v3 + 1.0f);
    int s = v0 + v1 + v2 + v3;
    sdata[tid] = s;
    __syncthreads();
    for (int off = 1; off < 256; off <<= 1) {
        int t = (tid >= off) ? sdata[tid - off] : 0;
        __syncthreads();
        sdata[tid] += t;
        __syncthreads();
    }
    if (tid == 255) bsum[blockIdx.x] = sdata[255];
    int run = sdata[tid] - s;
    if (base + 0 < n) excl[base + 0] = run; run += v0;
    if (base + 1 < n) excl[base + 1] = run; run += v1;
    if (base + 2 < n) excl[base + 2] = run; run += v2;
    if (base + 3 < n) excl[base + 3] = run;
}

__global__ __launch_bounds__(256) void scan2(int* __restrict__ bsum, int nb) {
    __shared__ int sdata[256];
    const int tid = threadIdx.x;
    int v = (tid < nb) ? bsum[tid] : 0;
    sdata[tid] = v;
    __syncthreads();
    for (int off = 1; off < 256; off <<= 1) {
        int t = (tid >= off) ? sdata[tid - off] : 0;
        __syncthreads();
        sdata[tid] += t;
        __syncthreads();
    }
    if (tid < nb) bsum[tid] = sdata[tid] - v;
}

// writes both rowptr and fill (atomic cursor working copy)
__global__ __launch_bounds__(256) void scan3(int* __restrict__ rowptr, int* __restrict__ fill,
                                             const int* __restrict__ bsum, int n, int E) {
    int i = blockIdx.x * 256 + threadIdx.x;
    if (i < n) {
        int v = rowptr[i] + bsum[i >> 10];
        rowptr[i] = v;
        fill[i] = v;
    }
    if (i == 0) rowptr[n] = E;
}

// ---------------- CSR fill: 8B-stride entries (.x = src), cursor in fill ----------------
__global__ __launch_bounds__(256) void csr_fill(const int* __restrict__ src, const int* __restrict__ dst,
                                                int* __restrict__ fill, int2* __restrict__ csr, int E) {
    int e = blockIdx.x * 256 + threadIdx.x;
    if (e >= E) return;
    int s = src[e], d = dst[e];
    int pos = atomicAdd(&fill[d], 1);
    csr[pos] = make_int2(s, 0);
}

// ---------------- fused prep: cast_x (42->48 pad, dis-prescale, bf16) + pad_w1 + 3x split_w ----------------
__global__ __launch_bounds__(256) void prep(const float* __restrict__ x, const float* __restrict__ dis,
                                            unsigned short* __restrict__ xs1,
                                            const float* __restrict__ W1, float* __restrict__ W1p,
                                            const float* __restrict__ W2, unsigned short* __restrict__ w2h,
                                            unsigned short* __restrict__ w2l,
                                            const float* __restrict__ W3, unsigned short* __restrict__ w3h,
                                            unsigned short* __restrict__ w3l,
                                            const float* __restrict__ W4, unsigned short* __restrict__ w4h,
                                            unsigned short* __restrict__ w4l,
                                            int n, int nbx) {
    int bi = blockIdx.x;
    if (bi < nbx) {                       // cast_x
        int gid = bi * 256 + threadIdx.x;
        int nd = gid / 48, c = gid - nd * 48;
        if (nd < n) {
            float v = (c < 42) ? x[(size_t)nd * 42 + c] * dis[nd] : 0.0f;
            xs1[(size_t)nd * 48 + c] = f2bf(v);
        }
        return;
    }
    bi -= nbx;
    if (bi < 24) {                        // pad_w1: [42][128] -> [48][128]
        int i = bi * 256 + threadIdx.x;
        int k = i >> 7;
        W1p[i] = (k < 42) ? W1[i] : 0.0f;
        return;
    }
    bi -= 24;
    if (bi < 128) {                       // split W2: [128][256] -> T hi/lo [256][128]
        int i = bi * 256 + threadIdx.x;
        int c = i >> 7, k = i & 127;
        float w = W2[(size_t)k * 256 + c];
        unsigned short h = f2bf(w);
        w2h[i] = h; w2l[i] = f2bf(w - bf2f(h));
        return;
    }
    bi -= 128;
    if (bi < 128) {                       // split W3: [256][128] -> T hi/lo [128][256]
        int i = bi * 256 + threadIdx.x;
        int c = i >> 8, k = i & 255;
        float w = W3[(size_t)k * 128 + c];
        unsigned short h = f2bf(w);
        w3h[i] = h; w3l[i] = f2bf(w - bf2f(h));
        return;
    }
    bi -= 128;
    {                                     // split W4: [128][64] -> T hi/lo [64][128]
        int i = bi * 256 + threadIdx.x;
        int c = i >> 7, k = i & 127;
        float w = W4[(size_t)k * 64 + c];
        unsigned short h = f2bf(w);
        w4h[i] = h; w4l[i] = f2bf(w - bf2f(h));
        return;
    }
}

// ---------------- bf16 prescaled aggregation: out[nd] = dis[nd] * (xs[nd] + sum xs[src]) ----------------
// FUSE 0: plain ; FUSE 1: relu(agg + (b*s+t))
template<int D, int FUSE>
__global__ __launch_bounds__(256) void agg_bf(const unsigned short* __restrict__ x, const float* __restrict__ dis,
                                              const int* __restrict__ rowptr, const int2* __restrict__ csr,
                                              const float* __restrict__ b, const float* __restrict__ g,
                                              const float* __restrict__ be, const float* __restrict__ rm,
                                              const float* __restrict__ rv,
                                              float* __restrict__ out, int n) {
    constexpr int CPE = D / 8;
    int gid = blockIdx.x * 256 + threadIdx.x;
    int nd = gid / CPE, c = gid - nd * CPE;
    if (nd >= n) return;

    float acc[8];
    {
        short8v v = *reinterpret_cast<const short8v*>(x + (size_t)nd * D + c * 8);
#pragma unroll
        for (int j = 0; j < 8; ++j) acc[j] = bf2f((unsigned short)v[j]);
    }
    const int r0 = rowptr[nd], r1 = rowptr[nd + 1];
    int i = r0;
    for (; i + 2 <= r1; i += 2) {
        int s0 = csr[i].x, s1 = csr[i + 1].x;
        short8v v0 = *reinterpret_cast<const short8v*>(x + (size_t)s0 * D + c * 8);
        short8v v1 = *reinterpret_cast<const short8v*>(x + (size_t)s1 * D + c * 8);
#pragma unroll
        for (int j = 0; j < 8; ++j) acc[j] += bf2f((unsigned short)v0[j]);
#pragma unroll
        for (int j = 0; j < 8; ++j) acc[j] += bf2f((unsigned short)v1[j]);
    }
    for (; i < r1; ++i) {
        int s0 = csr[i].x;
        short8v v = *reinterpret_cast<const short8v*>(x + (size_t)s0 * D + c * 8);
#pragma unroll
        for (int j = 0; j < 8; ++j) acc[j] += bf2f((unsigned short)v[j]);
    }

    float dn = dis[nd];
#pragma unroll
    for (int j = 0; j < 8; ++j) acc[j] *= dn;

    if (FUSE == 1) {
#pragma unroll
        for (int j = 0; j < 8; ++j) {
            int col = c * 8 + j;
            float sv = g[col] * rsqrtf(rv[col] + EPS);
            float bb = b[col] * sv + (be[col] - rm[col] * sv);
            acc[j] = fmaxf(acc[j] + bb, 0.0f);
        }
    }

    float4 o0, o1;
    o0.x = acc[0]; o0.y = acc[1]; o0.z = acc[2]; o0.w = acc[3];
    o1.x = acc[4]; o1.y = acc[5]; o1.z = acc[6]; o1.w = acc[7];
    float* op = out + (size_t)nd * D + c * 8;
    *reinterpret_cast<float4*>(op) = o0;
    *reinterpret_cast<float4*>(op + 4) = o1;
}

// ---------------- split-bf16 MFMA GEMM ----------------
// MODE 0: z=(acc+b)*s+t, relu ; MODE 1: z=acc*s ; MODE 2: z=relu(acc+b)*s+t
// OUTBF: write bf16 ; RS: multiply by dis[row]
template<int K, int DOUT, int MODE, int OUTBF, int RS>
__global__ __launch_bounds__(256) void gemm_mfma(const float* __restrict__ X,
                                                 const unsigned short* __restrict__ Wh,
                                                 const unsigned short* __restrict__ Wl,
                                                 const float* __restrict__ b, const float* __restrict__ g,
                                                 const float* __restrict__ be, const float* __restrict__ rm,
                                                 const float* __restrict__ rv, const float* __restrict__ dis,
                                                 void* __restrict__ outv, int n) {
    constexpr int BN = (DOUT < 128) ? DOUT : 128;
    constexpr int NT = BN / 16;
    constexpr int KSTEPS = K / 32;
    constexpr int LDA = 40;
    __shared__ unsigned short xh[64][LDA], xl[64][LDA];
    __shared__ unsigned short wh[BN][LDA], wl[BN][LDA];

    const int tid = threadIdx.x;
    const int wave = tid >> 6, lane = tid & 63;
    const int row0 = blockIdx.x * 64;
    const int col0 = blockIdx.y * BN;
    const int r_l = lane & 15;
    const int k_l = (lane >> 4) * 8;

    f32x4 acc[NT];
#pragma unroll
    for (int t = 0; t < NT; ++t) acc[t] = (f32x4){0.f, 0.f, 0.f, 0.f};

    for (int ks = 0; ks < KSTEPS; ++ks) {
        const int k0 = ks * 32;
        for (int i = tid; i < 64 * 8; i += 256) {
            int m = i >> 3, q = i & 7;
            int rr = row0 + m;
            float4 v = (rr < n) ? *reinterpret_cast<const float4*>(X + (size_t)rr * K + k0 + q * 4)
                                : make_float4(0.f, 0.f, 0.f, 0.f);
            unsigned short h0 = f2bf(v.x), h1 = f2bf(v.y), h2 = f2bf(v.z), h3 = f2bf(v.w);
            unsigned short l0 = f2bf(v.x - bf2f(h0)), l1 = f2bf(v.y - bf2f(h1));
            unsigned short l2 = f2bf(v.z - bf2f(h2)), l3 = f2bf(v.w - bf2f(h3));
            uint2 ph = make_uint2((unsigned)h0 | ((unsigned)h1 << 16), (unsigned)h2 | ((unsigned)h3 << 16));
            uint2 pl = make_uint2((unsigned)l0 | ((unsigned)l1 << 16), (unsigned)l2 | ((unsigned)l3 << 16));
            *reinterpret_cast<uint2*>(&xh[m][q * 4]) = ph;
            *reinterpret_cast<uint2*>(&xl[m][q * 4]) = pl;
        }
        for (int i = tid; i < BN * 4; i += 256) {
            int cc = i >> 2, q = i & 3;
            size_t goff = (size_t)(col0 + cc) * K + k0 + q * 8;
            *reinterpret_cast<uint4*>(&wh[cc][q * 8]) = *reinterpret_cast<const uint4*>(Wh + goff);
            *reinterpret_cast<uint4*>(&wl[cc][q * 8]) = *reinterpret_cast<const uint4*>(Wl + goff);
        }
        __syncthreads();

        short8v ah = *reinterpret_cast<const short8v*>(&xh[wave * 16 + r_l][k_l]);
        short8v al = *reinterpret_cast<const short8v*>(&xl[wave * 16 + r_l][k_l]);
#pragma unroll
        for (int t = 0; t < NT; ++t) {
            short8v bh = *reinterpret_cast<const short8v*>(&wh[t * 16 + r_l][k_l]);
            short8v bl = *reinterpret_cast<const short8v*>(&wl[t * 16 + r_l][k_l]);
            acc[t] = __builtin_amdgcn_mfma_f32_16x16x32_bf16(ah, bh, acc[t], 0, 0, 0);
            acc[t] = __builtin_amdgcn_mfma_f32_16x16x32_bf16(al, bh, acc[t], 0, 0, 0);
            acc[t] = __builtin_amdgcn_mfma_f32_16x16x32_bf16(ah, bl, acc[t], 0, 0, 0);
        }
        __syncthreads();
    }

    const int orow = row0 + wave * 16 + (lane >> 4) * 4;
    float dsc[4];
#pragma unroll
    for (int r = 0; r < 4; ++r)
        dsc[r] = (RS && orow + r < n) ? dis[orow + r] : 1.0f;

#pragma unroll
    for (int t = 0; t < NT; ++t) {
        int col = col0 + t * 16 + r_l;
        float s, tt, bias;
        if (MODE == 0 || MODE == 2) {
            float sv = g[col] * rsqrtf(rv[col] + EPS);
            s = sv; tt = be[col] - rm[col] * sv; bias = b[col];
        } else {
            s = g[col] * rsqrtf(rv[col] + EPS); tt = 0.f; bias = 0.f;
        }
#pragma unroll
        for (int r = 0; r < 4; ++r) {
            int rr = orow + r;
            if (rr < n) {
                float z = acc[t][r];
                if (MODE == 0)      { z = (z + bias) * s + tt; z = fmaxf(z, 0.0f); }
                else if (MODE == 1) { z = z * s; }
                else                { z = fmaxf(z + bias, 0.0f) * s + tt; }
                if (RS) z *= dsc[r];
                if (OUTBF) ((unsigned short*)outv)[(size_t)rr * DOUT + col] = f2bf(z);
                else       ((float*)outv)[(size_t)rr * DOUT + col] = z;
            }
        }
    }
}

// ---------------- f32 register-tiled GEMM (layer 1) ----------------
template<int K, int DOUT, int MODE, int OUTBF, int RS>
__global__ __launch_bounds__(256) void gemm_tile(const float* __restrict__ X, const float* __restrict__ W,
                                                 const float* __restrict__ b, const float* __restrict__ g,
                                                 const float* __restrict__ be, const float* __restrict__ rm,
                                                 const float* __restrict__ rv, const float* __restrict__ dis,
                                                 void* __restrict__ outv, int n) {
    constexpr int TM = 8;
    constexpr int TN = (DOUT >= 64) ? 8 : 4;
    constexpr int BN = (DOUT < 128) ? DOUT : 128;
    constexpr int BM = 256 * TM * TN / BN;
    constexpr int KT = (K % 32 == 0) ? 32 : K;
    constexpr int NTN = BN / TN;
    static_assert((BM / TM) * NTN == 256, "thread mapping");

    __shared__ float xs[BM][KT + 1];
    __shared__ float ws[KT][BN];

    const int tid = threadIdx.x;
    const int tn_idx = tid % NTN;
    const int tm_idx = tid / NTN;
    const int row0 = blockIdx.x * BM;
    const int col0 = blockIdx.y * BN;

    float acc[TM][TN];
#pragma unroll
    for (int i = 0; i < TM; ++i)
#pragma unroll
        for (int j = 0; j < TN; ++j) acc[i][j] = 0.0f;

    for (int k0 = 0; k0 < K; k0 += KT) {
        for (int i = tid; i < BM * KT / 4; i += 256) {
            int m = i / (KT / 4), kq = i - m * (KT / 4);
            int k = kq * 4;
            int rr = row0 + m;
            float4 v = (rr < n) ? *reinterpret_cast<const float4*>(X + (size_t)rr * K + k0 + k)
                                : make_float4(0.f, 0.f, 0.f, 0.f);
            xs[m][k + 0] = v.x; xs[m][k + 1] = v.y; xs[m][k + 2] = v.z; xs[m][k + 3] = v.w;
        }
        for (int i = tid; i < KT * BN / 4; i += 256) {
            int k = i / (BN / 4), cq = i - k * (BN / 4);
            float4 wv = *reinterpret_cast<const float4*>(W + (size_t)(k0 + k) * DOUT + col0 + cq * 4);
            *reinterpret_cast<float4*>(&ws[k][cq * 4]) = wv;
        }
        __syncthreads();

#pragma unroll 2
        for (int k = 0; k < KT; ++k) {
            float av[TM], bv[TN];
#pragma unroll
            for (int i = 0; i < TM; ++i) av[i] = xs[tm_idx * TM + i][k];
#pragma unroll
            for (int j = 0; j < TN; j += 4)
                *reinterpret_cast<float4*>(&bv[j]) = *reinterpret_cast<const float4*>(&ws[k][tn_idx * TN + j]);
#pragma unroll
            for (int i = 0; i < TM; ++i)
#pragma unroll
                for (int j = 0; j < TN; ++j)
                    acc[i][j] = fmaf(av[i], bv[j], acc[i][j]);
        }
        __syncthreads();
    }

    float s[TN], t[TN], bias[TN];
#pragma unroll
    for (int j = 0; j < TN; ++j) {
        int col = col0 + tn_idx * TN + j;
        if (MODE == 0 || MODE == 2) {
            float sv = g[col] * rsqrtf(rv[col] + EPS);
            s[j] = sv; t[j] = be[col] - rm[col] * sv; bias[j] = b[col];
        } else {
            s[j] = g[col] * rsqrtf(rv[col] + EPS); t[j] = 0.f; bias[j] = 0.f;
        }
    }

#pragma unroll
    for (int i = 0; i < TM; ++i) {
        int rr = row0 + tm_idx * TM + i;
        if (rr < n) {
            float dsc = RS ? dis[rr] : 1.0f;
            float o[TN];
#pragma unroll
            for (int j = 0; j < TN; ++j) {
                float z = acc[i][j];
                if (MODE == 0)      { z = (z + bias[j]) * s[j] + t[j]; z = fmaxf(z, 0.0f); }
                else if (MODE == 1) { z = z * s[j]; }
                else                { z = fmaxf(z + bias[j], 0.0f) * s[j] + t[j]; }
                if (RS) z *= dsc;
                o[j] = z;
            }
            if (OUTBF) {
                unsigned short* op = (unsigned short*)outv + (size_t)rr * DOUT + col0 + tn_idx * TN;
                unsigned int pk[TN / 2];
#pragma unroll
                for (int j2 = 0; j2 < TN / 2; ++j2)
                    pk[j2] = (unsigned)f2bf(o[2 * j2]) | ((unsigned)f2bf(o[2 * j2 + 1]) << 16);
#pragma unroll
                for (int j2 = 0; j2 < TN / 2; ++j2)
                    *reinterpret_cast<unsigned int*>(op + 2 * j2) = pk[j2];
            } else {
                float* op = (float*)outv + (size_t)rr * DOUT + col0 + tn_idx * TN;
#pragma unroll
                for (int j = 0; j < TN; j += 4)
                    *reinterpret_cast<float4*>(op + j) = *reinterpret_cast<const float4*>(&o[j]);
            }
        }
    }
}

// ---------------- fused classifier: [n][64] -> Lin64+ReLU+BN -> Lin32+ReLU+BN -> Lin2 ----------------
__global__ __launch_bounds__(256) void classifier_fused(
    const float* __restrict__ X,
    const float* __restrict__ cW1, const float* __restrict__ cb1,
    const float* __restrict__ cg1, const float* __restrict__ cbe1,
    const float* __restrict__ crm1, const float* __restrict__ crv1,
    const float* __restrict__ cW2, const float* __restrict__ cb2,
    const float* __restrict__ cg2, const float* __restrict__ cbe2,
    const float* __restrict__ crm2, const float* __restrict__ crv2,
    const float* __restrict__ cW3, const float* __restrict__ cb3,
    float* __restrict__ out, int n)
{
    __shared__ float xs[64][65];
    __shared__ float h1[64][65];
    __shared__ float h2[64][33];
    const int tid = threadIdx.x;
    const int row0 = blockIdx.x * 64;

    for (int i = tid; i < 64 * 16; i += 256) {
        int r = i >> 4, cq = i & 15;
        int rr = row0 + r;
        float4 v = (rr < n) ? *reinterpret_cast<const float4*>(X + (size_t)rr * 64 + cq * 4)
                            : make_float4(0.f, 0.f, 0.f, 0.f);
        xs[r][cq * 4 + 0] = v.x; xs[r][cq * 4 + 1] = v.y;
        xs[r][cq * 4 + 2] = v.z; xs[r][cq * 4 + 3] = v.w;
    }
    __syncthreads();

    {   // phase 1: 64 cols x 4 row-groups of 16
        const int col = tid & 63;
        const int rg  = tid >> 6;
        float sv = cg1[col] * rsqrtf(crv1[col] + EPS);
        float tt = cbe1[col] - crm1[col] * sv;
        float bias = cb1[col];
        float accv[16];
#pragma unroll
        for (int r = 0; r < 16; ++r) accv[r] = 0.f;
#pragma unroll 4
        for (int k = 0; k < 64; ++k) {
            float w = cW1[k * 64 + col];
#pragma unroll
            for (int r = 0; r < 16; ++r)
                accv[r] = fmaf(xs[rg * 16 + r][k], w, accv[r]);
        }
#pragma unroll
        for (int r = 0; r < 16; ++r)
            h1[rg * 16 + r][col] = fmaxf(accv[r] + bias, 0.f) * sv + tt;
    }
    __syncthreads();

    {   // phase 2: 32 cols x 8 row-groups of 8
        const int col = tid & 31;
        const int rg  = tid >> 5;
        float sv = cg2[col] * rsqrtf(crv2[col] + EPS);
        float tt = cbe2[col] - crm2[col] * sv;
        float bias = cb2[col];
        float accv[8];
#pragma unroll
        for (int r = 0; r < 8; ++r) accv[r] = 0.f;
#pragma unroll 4
        for (int k = 0; k < 64; ++k) {
            float w = cW2[k * 32 + col];
#pragma unroll
            for (int r = 0; r < 8; ++r)
                accv[r] = fmaf(h1[rg * 8 + r][k], w, accv[r]);
        }
#pragma unroll
        for (int r = 0; r < 8; ++r)
            h2[rg * 8 + r][col] = fmaxf(accv[r] + bias, 0.f) * sv + tt;
    }
    __syncthreads();

    if (tid < 64) {   // phase 3: one row per thread
        int rr = row0 + tid;
        if (rr < n) {
            float a0 = 0.f, a1 = 0.f;
#pragma unroll
            for (int k = 0; k < 32; ++k) {
                float h = h2[tid][k];
                a0 = fmaf(h, cW3[k * 2 + 0], a0);
                a1 = fmaf(h, cW3[k * 2 + 1], a1);
            }
            out[(size_t)rr * 2 + 0] = a0 + cb3[0];
            out[(size_t)rr * 2 + 1] = a1 + cb3[1];
        }
    }
}

// ---------------- launch ----------------

extern "C" void kernel_launch(void* const* d_in, const int* in_sizes, int n_in,
                              void* d_out, int out_size, void* d_ws, size_t ws_size,
                              hipStream_t stream) {
    const float* x  = (const float*)d_in[0];
    const int*   ei = (const int*)d_in[1];
    const int E = in_sizes[1] / 2;
    const int n = in_sizes[0] / 42;
    const int* src = ei;
    const int* dst = ei + E;

    const float *W1 = (const float*)d_in[2],  *b1 = (const float*)d_in[3],  *g1 = (const float*)d_in[4],
                *be1 = (const float*)d_in[5], *rm1 = (const float*)d_in[6], *rv1 = (const float*)d_in[7];
    const float *W2 = (const float*)d_in[8],  *b2 = (const float*)d_in[9],  *g2 = (const float*)d_in[10],
                *be2 = (const float*)d_in[11], *rm2 = (const float*)d_in[12], *rv2 = (const float*)d_in[13];
    const float *W3 = (const float*)d_in[14], *b3 = (const float*)d_in[15], *g3 = (const float*)d_in[16],
                *be3 = (const float*)d_in[17], *rm3 = (const float*)d_in[18], *rv3 = (const float*)d_in[19];
    const float *W4 = (const float*)d_in[20], *b4 = (const float*)d_in[21], *g4 = (const float*)d_in[22],
                *be4 = (const float*)d_in[23], *rm4 = (const float*)d_in[24], *rv4 = (const float*)d_in[25];
    const float *cW1 = (const float*)d_in[26], *cb1 = (const float*)d_in[27], *cg1 = (const float*)d_in[28],
                *cbe1 = (const float*)d_in[29], *crm1 = (const float*)d_in[30], *crv1 = (const float*)d_in[31];
    const float *cW2 = (const float*)d_in[32], *cb2 = (const float*)d_in[33], *cg2 = (const float*)d_in[34],
                *cbe2 = (const float*)d_in[35], *crm2 = (const float*)d_in[36], *crv2 = (const float*)d_in[37];
    const float *cW3 = (const float*)d_in[38], *cb3 = (const float*)d_in[39];

    // ---- workspace layout ----
    int2*  csr    = (int2*)d_ws;                         // E (8B entries, .x = src)
    float* bufA   = (float*)(csr + E);                   // n*128
    float* bufB   = bufA + (size_t)n * 128;              // n*256
    unsigned short* hbf = (unsigned short*)(bufB + (size_t)n * 256);  // n*128 bf16
    unsigned short* xs1 = hbf + (size_t)n * 128;         // n*48 bf16
    float* dis    = (float*)(xs1 + (size_t)n * 48);      // n
    int*   cnt    = (int*)(dis + n);                     // n
    int*   fill   = cnt + n;                             // n
    int*   rowptr = fill + n;                            // n+1
    int*   bsum   = rowptr + n + 1;                      // 256
    float* W1p    = (float*)(bsum + 256);                // 48*128
    unsigned short* w2h = (unsigned short*)(W1p + 48 * 128);  // 256*128
    unsigned short* w2l = w2h + 256 * 128;
    unsigned short* w3h = w2l + 256 * 128;               // 128*256
    unsigned short* w3l = w3h + 128 * 256;
    unsigned short* w4h = w3l + 128 * 256;               // 64*128
    unsigned short* w4l = w4h + 64 * 128;

    dim3 blk(256);
    auto nb = [](long total) { return dim3((unsigned)((total + 255) / 256)); };
    const int nscan = (n + 1023) / 1024;
    const int nbx = (int)(((long)n * 48 + 255) / 256);
    const float* nul = nullptr;

    // ---- CSR build + prep ----
    hipMemsetAsync(cnt, 0, (size_t)n * sizeof(int), stream);
    count_deg<<<nb(E), blk, 0, stream>>>(dst, cnt, E);
    scan1<<<dim3(nscan), blk, 0, stream>>>(cnt, rowptr, bsum, dis, n);
    scan2<<<dim3(1), blk, 0, stream>>>(bsum, nscan);
    scan3<<<nb(n), blk, 0, stream>>>(rowptr, fill, bsum, n, E);
    csr_fill<<<nb(E), blk, 0, stream>>>(src, dst, fill, csr, E);
    prep<<<dim3(nbx + 24 + 128 + 128 + 32), blk, 0, stream>>>(x, dis, xs1, W1, W1p,
                                                              W2, w2h, w2l, W3, w3h, w3l,
                                                              W4, w4h, w4l, n, nbx);

    // ---- Layer 1: agg_bf<48>(xs1)->bufA ; gemm 48->128 BN+ReLU, row-scale, bf16 -> hbf
    agg_bf<48, 0><<<nb((long)n * 6), blk, 0, stream>>>(xs1, dis, rowptr, csr, nul, nul, nul, nul, nul, bufA, n);
    gemm_tile<48, 128, 0, 1, 1><<<dim3((n + 127) / 128, 1), blk, 0, stream>>>(bufA, W1p, b1, g1, be1, rm1, rv1, dis, (void*)hbf, n);

    // ---- Layer 2: agg_bf<128>(hbf)->bufA ; gemm 128->256 BN+ReLU -> bufB (f32)
    agg_bf<128, 0><<<nb((long)n * 16), blk, 0, stream>>>(hbf, dis, rowptr, csr, nul, nul, nul, nul, nul, bufA, n);
    gemm_mfma<128, 256, 0, 0, 0><<<dim3((n + 63) / 64, 2), blk, 0, stream>>>(bufA, w2h, w2l, b2, g2, be2, rm2, rv2, nul, (void*)bufB, n);

    // ---- Layer 3: gemm 256->128 (col-scale s3, row-scale dis) -> hbf ; agg + fused bias/bn/relu -> bufA
    gemm_mfma<256, 128, 1, 1, 1><<<dim3((n + 63) / 64, 1), blk, 0, stream>>>(bufB, w3h, w3l, b3, g3, be3, rm3, rv3, dis, (void*)hbf, n);
    agg_bf<128, 1><<<nb((long)n * 16), blk, 0, stream>>>(hbf, dis, rowptr, csr, b3, g3, be3, rm3, rv3, bufA, n);

    // ---- Layer 4: gemm 128->64 (col-scale s4, row-scale dis) -> hbf ; agg + fused bias/bn/relu -> bufB
    gemm_mfma<128, 64, 1, 1, 1><<<dim3((n + 63) / 64, 1), blk, 0, stream>>>(bufA, w4h, w4l, b4, g4, be4, rm4, rv4, dis, (void*)hbf, n);
    agg_bf<64, 1><<<nb((long)n * 8), blk, 0, stream>>>(hbf, dis, rowptr, csr, b4, g4, be4, rm4, rv4, bufB, n);

    // ---- Fused classifier
    classifier_fused<<<dim3((n + 63) / 64), blk, 0, stream>>>(bufB, cW1, cb1, cg1, cbe1, crm1, crv1,
                                                              cW2, cb2, cg2, cbe2, crm2, crv2,
                                                              cW3, cb3, (float*)d_out, n);
}